// Round 8
// baseline (238.776 us; speedup 1.0000x reference)
//
#include <hip/hip_runtime.h>
#include <math.h>

#define NPTS 16384
#define DIN 13
#define KNN 8

typedef _Float16 half8 __attribute__((ext_vector_type(8)));
typedef float f32x4 __attribute__((ext_vector_type(4)));
typedef float f32x16 __attribute__((ext_vector_type(16)));

__device__ __forceinline__ float silu(float v) {
    return v / (1.0f + __expf(-v));
}

// branchless scalar top-8 insert (sorted ascending d0..d7), med3 chain
#define MED3(v, a, b) __builtin_amdgcn_fmed3f((v), (a), (b))
#define INS8V(v) {                      \
    d7 = MED3((v), d6, d7);             \
    d6 = MED3((v), d5, d6);             \
    d5 = MED3((v), d4, d5);             \
    d4 = MED3((v), d3, d4);             \
    d3 = MED3((v), d2, d3);             \
    d2 = MED3((v), d1, d2);             \
    d1 = MED3((v), d0, d1);             \
    d0 = fminf((v), d0); }

#define CSW(p, q) { float lo_ = fminf(m##p, m##q); float hi_ = fmaxf(m##p, m##q); m##p = lo_; m##q = hi_; }

// merge my sorted-asc scalars with lane^mask partner's; keep 8 smallest sorted
#define MERGE8(mask) {                                   \
    float b0 = __shfl_xor(d0, (mask), 64);               \
    float b1 = __shfl_xor(d1, (mask), 64);               \
    float b2 = __shfl_xor(d2, (mask), 64);               \
    float b3 = __shfl_xor(d3, (mask), 64);               \
    float b4 = __shfl_xor(d4, (mask), 64);               \
    float b5 = __shfl_xor(d5, (mask), 64);               \
    float b6 = __shfl_xor(d6, (mask), 64);               \
    float b7 = __shfl_xor(d7, (mask), 64);               \
    float m0 = fminf(d0, b7), m1 = fminf(d1, b6);        \
    float m2 = fminf(d2, b5), m3 = fminf(d3, b4);        \
    float m4 = fminf(d4, b3), m5 = fminf(d5, b2);        \
    float m6 = fminf(d6, b1), m7 = fminf(d7, b0);        \
    CSW(0,4) CSW(1,5) CSW(2,6) CSW(3,7)                  \
    CSW(0,2) CSW(1,3) CSW(4,6) CSW(5,7)                  \
    CSW(0,1) CSW(2,3) CSW(4,5) CSW(6,7)                  \
    d0 = m0; d1 = m1; d2 = m2; d3 = m3;                  \
    d4 = m4; d5 = m5; d6 = m6; d7 = m7; }

// ---- K1: encoder MLP -> x(f32), H/L/YH/YL(f16 splits), sq(f32), accb ----
__global__ __launch_bounds__(64) void k_encoder(
    const float* __restrict__ x_pfc,
    const float* __restrict__ W1, const float* __restrict__ b1,
    const float* __restrict__ W2, const float* __restrict__ b2,
    const float* __restrict__ W3, const float* __restrict__ b3,
    const float* __restrict__ We, const float* __restrict__ be,
    float* __restrict__ xo, _Float16* __restrict__ H, _Float16* __restrict__ L,
    _Float16* __restrict__ YH, _Float16* __restrict__ YL,
    float* __restrict__ SQF, float* __restrict__ ACC)
{
    __shared__ float sW1[DIN * 8];
    __shared__ float sb1[8];
    __shared__ float sW2[8 * 16];
    __shared__ float sb2[16];
    __shared__ float sW3[16 * 15];
    __shared__ float sb3[15];
    __shared__ float sWe[16 * 16];   // top half of We (rows 0..15)
    __shared__ float sbe[16];
    int t = threadIdx.x;
    for (int q = t; q < DIN * 8; q += 64) sW1[q] = W1[q];
    for (int q = t; q < 8; q += 64) sb1[q] = b1[q];
    for (int q = t; q < 8 * 16; q += 64) sW2[q] = W2[q];
    for (int q = t; q < 16; q += 64) sb2[q] = b2[q];
    for (int q = t; q < 16 * 15; q += 64) sW3[q] = W3[q];
    for (int q = t; q < 15; q += 64) sb3[q] = b3[q];
    for (int q = t; q < 16 * 16; q += 64) sWe[q] = We[q];
    for (int q = t; q < 16; q += 64) sbe[q] = be[q];
    __syncthreads();

    int i = blockIdx.x * 64 + t;
    float in[DIN];
#pragma unroll
    for (int d = 0; d < DIN; ++d) in[d] = x_pfc[i * DIN + d];

    float a1[8];
#pragma unroll
    for (int h = 0; h < 8; ++h) a1[h] = sb1[h];
#pragma unroll
    for (int d = 0; d < DIN; ++d) {
        float v = in[d];
#pragma unroll
        for (int h = 0; h < 8; ++h) a1[h] += v * sW1[d * 8 + h];
    }
#pragma unroll
    for (int h = 0; h < 8; ++h) a1[h] = silu(a1[h]);

    float a2[16];
#pragma unroll
    for (int h = 0; h < 16; ++h) a2[h] = sb2[h];
#pragma unroll
    for (int d = 0; d < 8; ++d) {
        float v = a1[d];
#pragma unroll
        for (int h = 0; h < 16; ++h) a2[h] += v * sW2[d * 16 + h];
    }
#pragma unroll
    for (int h = 0; h < 16; ++h) a2[h] = silu(a2[h]);

    float a3[15];
#pragma unroll
    for (int h = 0; h < 15; ++h) a3[h] = sb3[h];
#pragma unroll
    for (int d = 0; d < 16; ++d) {
        float v = a2[d];
#pragma unroll
        for (int h = 0; h < 15; ++h) a3[h] += v * sW3[d * 15 + h];
    }

    float xr[16];
#pragma unroll
    for (int h = 0; h < 15; ++h) xr[h] = a3[h];
    xr[15] = in[DIN - 1];

    float s = 0.0f;
#pragma unroll
    for (int d = 0; d < 16; ++d) s += xr[d] * xr[d];

    float accb[16];
#pragma unroll
    for (int h = 0; h < 16; ++h) accb[h] = sbe[h];
#pragma unroll
    for (int d = 0; d < 16; ++d) {
        float v = xr[d];
#pragma unroll
        for (int h = 0; h < 16; ++h) accb[h] += v * sWe[d * 16 + h];
    }

#pragma unroll
    for (int d = 0; d < 16; ++d) {
        xo[i * 16 + d] = xr[d];
        _Float16 h = (_Float16)xr[d];
        _Float16 l = (_Float16)(xr[d] - (float)h);
        H[(size_t)i * 16 + d] = h;
        L[(size_t)i * 16 + d] = l;
        float y = -2.0f * xr[d];
        _Float16 yh = (_Float16)y;
        _Float16 yl = (_Float16)(y - (float)yh);
        YH[(size_t)i * 16 + d] = yh;
        YL[(size_t)i * 16 + d] = yl;
        ACC[(size_t)i * 16 + d] = accb[d];
    }
    SQF[i] = s;
}

// ---- K2: MFMA 32x32 KNN, j-split two-pass ----
// Grid 1024 = 512 i-tiles x 2 j-halves. Block = 8 waves; wave scans 1024 j
// of its half in 32-j tiles. C = 3x mfma_32x32x16 (h.yh + l.yh + h.yl, fp32
// acc), v = c + sq[j]. Pass 1: branchless per-lane top-8 values (1 col/lane).
// Merge -> exact LOCAL kth per col. Pass 2: recompute bit-identically,
// v <= kth -> append (v,id) to LDS cands (<=16). Dump 16 (v,id)/col/half.
__global__ __launch_bounds__(512, 8) void k_knn(
    const _Float16* __restrict__ H, const _Float16* __restrict__ L,
    const _Float16* __restrict__ YH, const _Float16* __restrict__ YL,
    const float* __restrict__ SQF,
    float* __restrict__ CV, int* __restrict__ CI)
{
    __shared__ float wl[8 * 8 * 32];   // [slot][wave][col] = 8 KB
    __shared__ float kthv[32];
    __shared__ int cnt[32];
    __shared__ float candv[32 * 16];
    __shared__ int candi[32 * 16];

    int t = threadIdx.x;
    int w = t >> 6;
    int lane = t & 63;
    int r31 = lane & 31;
    int hh = lane >> 5;          // k-half for A/B frags, row offset for C
    int ih = blockIdx.x >> 1;
    int jh = blockIdx.x & 1;
    int i0 = ih * 32;

    if (t < 32) cnt[t] = 0;
    candv[t & 511] = 3.4e38f;
    candi[t & 511] = i0 + ((t & 511) >> 4);   // benign valid default
    // no barrier needed yet: only this block's threads touch these, and the
    // first use is after the pass-1 __syncthreads below.

    // B frags: B[k][n], n = lane&31 = col i, k = hh*8 + b
    int gi = i0 + r31;
    half8 B1 = *(const half8*)(YH + (size_t)gi * 16 + hh * 8);
    half8 B2 = *(const half8*)(YL + (size_t)gi * 16 + hh * 8);

    float d0 = 3.4e38f, d1 = 3.4e38f, d2 = 3.4e38f, d3 = 3.4e38f;
    float d4 = 3.4e38f, d5 = 3.4e38f, d6 = 3.4e38f, d7 = 3.4e38f;

    int jw = jh * 8192 + w * 1024;
    const _Float16* pH = H + ((size_t)(jw + r31)) * 16 + hh * 8;
    const _Float16* pL = L + ((size_t)(jw + r31)) * 16 + hh * 8;
    const float* pS = SQF + jw + 4 * hh;

    // ---- pass 1: values only ----
    for (int tt = 0; tt < 32; ++tt) {
        half8 Ah = *(const half8*)pH;
        half8 Al = *(const half8*)pL;
        f32x4 s0 = *(const f32x4*)(pS);
        f32x4 s1 = *(const f32x4*)(pS + 8);
        f32x4 s2 = *(const f32x4*)(pS + 16);
        f32x4 s3 = *(const f32x4*)(pS + 24);

        f32x16 c = {};
        c = __builtin_amdgcn_mfma_f32_32x32x16_f16(Ah, B1, c, 0, 0, 0);
        c = __builtin_amdgcn_mfma_f32_32x32x16_f16(Al, B1, c, 0, 0, 0);
        c = __builtin_amdgcn_mfma_f32_32x32x16_f16(Ah, B2, c, 0, 0, 0);

#pragma unroll
        for (int g = 0; g < 4; ++g) {
            f32x4 sg = (g == 0) ? s0 : (g == 1) ? s1 : (g == 2) ? s2 : s3;
#pragma unroll
            for (int q = 0; q < 4; ++q) {
                float v = c[g * 4 + q] + sg[q];
                INS8V(v);
            }
        }
        pH += 32 * 16;
        pL += 32 * 16;
        pS += 32;
    }

    // lanes r31 and r31+32 serve the same column -> merge
    MERGE8(32);
    if (lane < 32) {
        wl[(0 * 8 + w) * 32 + r31] = d0;
        wl[(1 * 8 + w) * 32 + r31] = d1;
        wl[(2 * 8 + w) * 32 + r31] = d2;
        wl[(3 * 8 + w) * 32 + r31] = d3;
        wl[(4 * 8 + w) * 32 + r31] = d4;
        wl[(5 * 8 + w) * 32 + r31] = d5;
        wl[(6 * 8 + w) * 32 + r31] = d6;
        wl[(7 * 8 + w) * 32 + r31] = d7;
    }
    __syncthreads();

    // exact local kth per column (this j-half)
    if (t < 32) {
        float d0 = 3.4e38f, d1 = 3.4e38f, d2 = 3.4e38f, d3 = 3.4e38f;
        float d4 = 3.4e38f, d5 = 3.4e38f, d6 = 3.4e38f, d7 = 3.4e38f;
        for (int w2 = 0; w2 < 8; ++w2) {
#pragma unroll
            for (int k = 0; k < 8; ++k) {
                float v = wl[(k * 8 + w2) * 32 + t];
                INS8V(v);
            }
        }
        kthv[t] = d7;
    }
    __syncthreads();

    float kth = kthv[r31];

    // ---- pass 2: bit-identical recompute, collect (v,id) ----
    pH = H + ((size_t)(jw + r31)) * 16 + hh * 8;
    pL = L + ((size_t)(jw + r31)) * 16 + hh * 8;
    pS = SQF + jw + 4 * hh;

    for (int tt = 0; tt < 32; ++tt) {
        half8 Ah = *(const half8*)pH;
        half8 Al = *(const half8*)pL;
        f32x4 s0 = *(const f32x4*)(pS);
        f32x4 s1 = *(const f32x4*)(pS + 8);
        f32x4 s2 = *(const f32x4*)(pS + 16);
        f32x4 s3 = *(const f32x4*)(pS + 24);

        f32x16 c = {};
        c = __builtin_amdgcn_mfma_f32_32x32x16_f16(Ah, B1, c, 0, 0, 0);
        c = __builtin_amdgcn_mfma_f32_32x32x16_f16(Al, B1, c, 0, 0, 0);
        c = __builtin_amdgcn_mfma_f32_32x32x16_f16(Ah, B2, c, 0, 0, 0);

        float v[16];
#pragma unroll
        for (int g = 0; g < 4; ++g) {
            f32x4 sg = (g == 0) ? s0 : (g == 1) ? s1 : (g == 2) ? s2 : s3;
#pragma unroll
            for (int q = 0; q < 4; ++q) v[g * 4 + q] = c[g * 4 + q] + sg[q];
        }
        float vm = v[0];
#pragma unroll
        for (int r = 1; r < 16; ++r) vm = fminf(vm, v[r]);

        if (__any(vm <= kth)) {
            int j0 = jw + tt * 32;
#pragma unroll
            for (int r = 0; r < 16; ++r) {
                bool hit = v[r] <= kth;
                if (__any(hit)) {
                    if (hit) {
                        int row = (r & 3) + 8 * (r >> 2) + 4 * hh;
                        int p = atomicAdd(&cnt[r31], 1);
                        if (p < 16) {
                            candi[r31 * 16 + p] = j0 + row;
                            candv[r31 * 16 + p] = v[r];
                        }
                    }
                }
            }
        }
        pH += 32 * 16;
        pL += 32 * 16;
        pS += 32;
    }
    __syncthreads();

    // dump 16 (v,id) per column for this half; thread t -> (col t>>4, slot t&15)
    {
        int col = t >> 4;
        int s = t & 15;
        size_t base = ((size_t)jh * NPTS + (i0 + col)) * 16 + s;
        CV[base] = candv[col * 16 + s];
        CI[base] = candi[col * 16 + s];
    }
}

// ---- K2b: merge the two j-half candidate sets -> exact top-8 ids ----
__global__ __launch_bounds__(256) void k_merge(
    const float* __restrict__ CV, const int* __restrict__ CI,
    int* __restrict__ knn_idx)
{
    int i = blockIdx.x * 256 + threadIdx.x;
    const float* v0 = CV + (size_t)i * 16;
    const float* v1 = CV + ((size_t)NPTS + i) * 16;

    float va[32];
#pragma unroll
    for (int s = 0; s < 16; ++s) va[s] = v0[s];
#pragma unroll
    for (int s = 0; s < 16; ++s) va[16 + s] = v1[s];

    float d0 = 3.4e38f, d1 = 3.4e38f, d2 = 3.4e38f, d3 = 3.4e38f;
    float d4 = 3.4e38f, d5 = 3.4e38f, d6 = 3.4e38f, d7 = 3.4e38f;
#pragma unroll
    for (int s = 0; s < 32; ++s) INS8V(va[s]);

    const int* i0p = CI + (size_t)i * 16;
    const int* i1p = CI + ((size_t)NPTS + i) * 16;
    int p = 0;
#pragma unroll
    for (int s = 0; s < 32; ++s) {
        int id = (s < 16) ? i0p[s] : i1p[s - 16];
        if (va[s] <= d7 && p < KNN) {
            knn_idx[(size_t)i * KNN + p] = id;
            ++p;
        }
    }
}

// ---- K3: edge conv + head MLP, 8 lanes per point ----
__global__ __launch_bounds__(256) void k_head(
    const float* __restrict__ x, const int* __restrict__ knn_idx,
    const float* __restrict__ x_pfc, const float* __restrict__ ACC,
    const float* __restrict__ We,
    const float* __restrict__ Wf1, const float* __restrict__ bf1,
    const float* __restrict__ Wf2, const float* __restrict__ bf2,
    float* __restrict__ out)
{
    __shared__ float sWe2[16 * 16];   // bottom half of We (rows 16..31)
    __shared__ float sWf1[16 * 32];
    __shared__ float sbf1[32];
    __shared__ float sWf2[32 * 16];
    __shared__ float sbf2[16];
    int t = threadIdx.x;
    for (int q = t; q < 16 * 16; q += 256) sWe2[q] = We[256 + q];
    for (int q = t; q < 16 * 32; q += 256) sWf1[q] = Wf1[q];
    for (int q = t; q < 32; q += 256) sbf1[q] = bf1[q];
    for (int q = t; q < 32 * 16; q += 256) sWf2[q] = Wf2[q];
    for (int q = t; q < 16; q += 256) sbf2[q] = bf2[q];
    __syncthreads();

    int i = blockIdx.x * 32 + (t >> 3);
    int e = t & 7;

    int j = knn_idx[(size_t)i * 8 + e];

    float xd[16];
    {
        const f32x4* xiv = (const f32x4*)(x + (size_t)i * 16);
        const f32x4* xjv = (const f32x4*)(x + (size_t)j * 16);
#pragma unroll
        for (int q = 0; q < 4; ++q) {
            f32x4 a = xjv[q], b = xiv[q];
#pragma unroll
            for (int r = 0; r < 4; ++r) xd[q * 4 + r] = a[r] - b[r];
        }
    }

    float acc[16];
    {
        const f32x4* av = (const f32x4*)(ACC + (size_t)i * 16);
#pragma unroll
        for (int q = 0; q < 4; ++q) {
            f32x4 a = av[q];
#pragma unroll
            for (int r = 0; r < 4; ++r) acc[q * 4 + r] = a[r];
        }
    }
#pragma unroll
    for (int d = 0; d < 16; ++d) {
        float v = xd[d];
#pragma unroll
        for (int h = 0; h < 16; ++h) acc[h] += v * sWe2[d * 16 + h];
    }

    float feats[16];
#pragma unroll
    for (int h = 0; h < 16; ++h) feats[h] = silu(acc[h]);

    // butterfly mean over the 8 lanes of this point
#pragma unroll
    for (int mask = 1; mask <= 4; mask <<= 1) {
#pragma unroll
        for (int h = 0; h < 16; ++h) feats[h] += __shfl_xor(feats[h], mask, 64);
    }
#pragma unroll
    for (int h = 0; h < 16; ++h) feats[h] *= 0.125f;

    float f1[32];
#pragma unroll
    for (int h = 0; h < 32; ++h) f1[h] = sbf1[h];
#pragma unroll
    for (int k = 0; k < 16; ++k) {
        float v = feats[k];
#pragma unroll
        for (int h = 0; h < 32; ++h) f1[h] += v * sWf1[k * 32 + h];
    }
#pragma unroll
    for (int h = 0; h < 32; ++h) f1[h] = silu(f1[h]);

    float f2[16];
#pragma unroll
    for (int h = 0; h < 16; ++h) f2[h] = sbf2[h];
#pragma unroll
    for (int k = 0; k < 32; ++k) {
        float v = f1[k];
#pragma unroll
        for (int h = 0; h < 16; ++h) f2[h] += v * sWf2[k * 16 + h];
    }

    // stores: lanes 0-3 write f2 (16 floats), lanes 4-7 write x_pfc (13)
    if (e < 4) {
#pragma unroll
        for (int q = 0; q < 4; ++q)
            out[(size_t)i * 29 + e * 4 + q] = f2[e * 4 + q];
    } else {
        int d00 = (e - 4) * 4;
#pragma unroll
        for (int q = 0; q < 4; ++q) {
            int d = d00 + q;
            if (d < DIN) out[(size_t)i * 29 + 16 + d] = x_pfc[i * DIN + d];
        }
    }
}

extern "C" void kernel_launch(void* const* d_in, const int* in_sizes, int n_in,
                              void* d_out, int out_size, void* d_ws, size_t ws_size,
                              hipStream_t stream)
{
    const float* x_pfc = (const float*)d_in[0];
    const float* W1 = (const float*)d_in[1];
    const float* b1 = (const float*)d_in[2];
    const float* W2 = (const float*)d_in[3];
    const float* b2 = (const float*)d_in[4];
    const float* W3 = (const float*)d_in[5];
    const float* b3 = (const float*)d_in[6];
    const float* We = (const float*)d_in[7];
    const float* be = (const float*)d_in[8];
    const float* Wf1 = (const float*)d_in[9];
    const float* bf1 = (const float*)d_in[10];
    const float* Wf2 = (const float*)d_in[11];
    const float* bf2 = (const float*)d_in[12];
    float* out = (float*)d_out;

    float* xw = (float*)d_ws;                         // N*16 f32
    int* idxw = (int*)(xw + (size_t)NPTS * 16);       // N*8 i32
    float* ACCa = (float*)(idxw + (size_t)NPTS * 8);  // N*16 f32
    _Float16* Ha = (_Float16*)(ACCa + (size_t)NPTS * 16);  // N*16 f16
    _Float16* La = Ha + (size_t)NPTS * 16;
    _Float16* YHa = La + (size_t)NPTS * 16;
    _Float16* YLa = YHa + (size_t)NPTS * 16;
    float* SQFa = (float*)(YLa + (size_t)NPTS * 16);  // N f32
    float* CVa = SQFa + NPTS;                         // 2*N*16 f32
    int* CIa = (int*)(CVa + (size_t)2 * NPTS * 16);   // 2*N*16 i32

    hipLaunchKernelGGL(k_encoder, dim3(NPTS / 64), dim3(64), 0, stream,
                       x_pfc, W1, b1, W2, b2, W3, b3, We, be,
                       xw, Ha, La, YHa, YLa, SQFa, ACCa);
    hipLaunchKernelGGL(k_knn, dim3(NPTS / 32 * 2), dim3(512), 0, stream,
                       Ha, La, YHa, YLa, SQFa, CVa, CIa);
    hipLaunchKernelGGL(k_merge, dim3(NPTS / 256), dim3(256), 0, stream,
                       CVa, CIa, idxw);
    hipLaunchKernelGGL(k_head, dim3(NPTS / 32), dim3(256), 0, stream,
                       xw, idxw, x_pfc, ACCa, We, Wf1, bf1, Wf2, bf2, out);
}